// Round 7
// baseline (342.876 us; speedup 1.0000x reference)
//
#include <hip/hip_runtime.h>
#include <stdint.h>

#define NEGF (-1e30f)

typedef unsigned short ushort_t;
typedef unsigned char uchar_t;
typedef __attribute__((ext_vector_type(2))) long v2i64;
typedef __attribute__((ext_vector_type(4))) float f32x4;

constexpr int cB = 4, cT = 256, cU = 64, cU1 = 65, cV = 1024, cF = 80, cH = 512, cJ = 512;
constexpr int cM = cB * cT * cU1; // 66560
constexpr int cTU = cT * cU1;     // 16640 (per-batch (u,t) plane: u*256+t)

// Padé(2,2) tanh + clamp: max err ~0.016, far below fp8-e4m3 half-step; no v_exp.
__device__ __forceinline__ float tanh_fast(float x){
  float t = x * x;
  float num = x * (27.f + t);
  float den = fmaf(9.f, t, 27.f);
  float r = num * __builtin_amdgcn_rcpf(den);
  return fminf(1.f, fmaxf(-1.f, r));
}

__device__ __forceinline__ float logadd(float x, float y){
  float m = fmaxf(x, y);
  return m + __logf(1.f + __expf(-fabsf(x - y)));
}

__device__ __forceinline__ int pk8(float a, float b, float c, float d){
  int v = __builtin_amdgcn_cvt_pk_fp8_f32(a, b, 0, false);
  v = __builtin_amdgcn_cvt_pk_fp8_f32(c, d, v, true);
  return v;
}

__device__ __forceinline__ void gload16(const void* g, void* l){
  __builtin_amdgcn_global_load_lds(
      (__attribute__((address_space(1))) void*)(g),
      (__attribute__((address_space(3))) void*)(l), 16, 0, 0);
}

// ------------- fused prologue: 3 independent jobs in one dispatch -------------
// bid 0..39   : Wcomb(80,512)  = W_enc @ W_jenc
// bid 40..169 : dmatb(260,512) = emb[padded] @ W_jdec + b_j
// bid 170..201: WTf8 fp8 fragment-order transpose of 32*W_out (2-ks-packed)
__global__ __launch_bounds__(256) void k_pre(
    const float* __restrict__ W_enc, const float* __restrict__ W_jenc,
    float* __restrict__ Wcomb,
    const float* __restrict__ emb, const int* __restrict__ targets,
    const float* __restrict__ W_jdec, const float* __restrict__ b_j,
    float* __restrict__ dmatb,
    const float* __restrict__ W_out, uchar_t* __restrict__ WTf8)
{
  __shared__ float sA[4][512];
  int bid = blockIdx.x;
  int tid = threadIdx.x;

  if (bid < 170){
    bool isW = (bid < 40);
    int id = isW ? bid : bid - 40;
    int bx = id & 1, by = id >> 1;
    int m0 = by * 4;
    int col = bx * 256 + tid;
    const float* Bm = isW ? W_jenc : W_jdec;
    for (int i = tid; i < 4 * 512; i += 256){
      int r = i >> 9, c = i & 511;
      if (isW){
        sA[r][c] = W_enc[(size_t)(m0 + r) * 512 + c];
      } else {
        int row = m0 + r;
        int b = row / cU1, u = row % cU1;
        int src = (u == 0) ? 0 : targets[b * cU + (u - 1)];
        sA[r][c] = emb[(size_t)src * cH + c];
      }
    }
    __syncthreads();
    float a0 = 0.f, a1 = 0.f, a2 = 0.f, a3 = 0.f;
#pragma unroll 8
    for (int k = 0; k < 512; k++){
      float bv = Bm[(size_t)k * cJ + col];
      a0 = fmaf(sA[0][k], bv, a0);
      a1 = fmaf(sA[1][k], bv, a1);
      a2 = fmaf(sA[2][k], bv, a2);
      a3 = fmaf(sA[3][k], bv, a3);
    }
    float bb = isW ? 0.f : b_j[col];
    float* C = isW ? Wcomb : dmatb;
    C[(size_t)(m0 + 0) * cJ + col] = a0 + bb;
    C[(size_t)(m0 + 1) * cJ + col] = a1 + bb;
    C[(size_t)(m0 + 2) * cJ + col] = a2 + bb;
    C[(size_t)(m0 + 3) * cJ + col] = a3 + bb;
  } else {
    // WTf8[((bn*8+ksp)*16 + nt16)*1024 + lane*16]: 16 B = frag(ks=2ksp) || frag(ks=2ksp+1)
    int id = bid - 170;                  // 0..31
    int bn = id & 3, ksp = id >> 2;      // ksp 0..7
    int lane = tid & 63, nth = tid >> 6;
    int c16 = lane & 15, quad = lane >> 4;
    int jA = ksp * 64 + quad * 8;
#pragma unroll
    for (int i = 0; i < 4; i++){
      int nt16 = nth * 4 + i;
      int n = bn * 256 + nt16 * 16 + c16;
      unsigned int p[4];
#pragma unroll
      for (int h = 0; h < 4; h++){
        int j0 = jA + (h >> 1) * 32 + (h & 1) * 4;
        float w0 = W_out[(size_t)(j0 + 0) * cV + n] * 32.f;
        float w1 = W_out[(size_t)(j0 + 1) * cV + n] * 32.f;
        float w2 = W_out[(size_t)(j0 + 2) * cV + n] * 32.f;
        float w3 = W_out[(size_t)(j0 + 3) * cV + n] * 32.f;
        p[h] = (unsigned)pk8(w0, w1, w2, w3);
      }
      uint4 pack; pack.x = p[0]; pack.y = p[1]; pack.z = p[2]; pack.w = p[3];
      *(uint4*)(WTf8 + (((size_t)(bn * 8 + ksp) * 16 + nt16) * 64 + lane) * 16) = pack;
    }
  }
}

// ------------- e = inputs @ Wcomb  (K=80), 4 rows/block -------------
__global__ void k_gemm_e(const float* __restrict__ A, const float* __restrict__ Bm,
                         float* __restrict__ C){
  __shared__ float sA[4][80];
  int m0 = blockIdx.y * 4;
  int col = blockIdx.x * 256 + threadIdx.x;
  for (int i = threadIdx.x; i < 4 * 80; i += 256)
    sA[i / 80][i % 80] = A[(size_t)(m0 + i / 80) * 80 + (i % 80)];
  __syncthreads();
  float a0 = 0.f, a1 = 0.f, a2 = 0.f, a3 = 0.f;
#pragma unroll 8
  for (int k = 0; k < 80; k++){
    float bv = Bm[(size_t)k * cJ + col];
    a0 = fmaf(sA[0][k], bv, a0);
    a1 = fmaf(sA[1][k], bv, a1);
    a2 = fmaf(sA[2][k], bv, a2);
    a3 = fmaf(sA[3][k], bv, a3);
  }
  C[(size_t)(m0 + 0) * cJ + col] = a0;
  C[(size_t)(m0 + 1) * cJ + col] = a1;
  C[(size_t)(m0 + 2) * cJ + col] = a2;
  C[(size_t)(m0 + 3) * cJ + col] = a3;
}

// ------------- H fp8 fragment-order, t-minor, coalesced via LDS bounce -------------
__global__ __launch_bounds__(256) void k_hf(const float* __restrict__ e,
                                            const float* __restrict__ dmatb,
                                            uchar_t* __restrict__ Hbf8){
  __shared__ uchar_t sH[16 * 520];    // 16 rows x 512 B, pad 8 B
  int tid = threadIdx.x;
  int wid = tid >> 6, lane = tid & 63;
  int c16 = lane & 15, quad = lane >> 4;
  int bm = blockIdx.x;
  int bu = bm >> 1, thalf = bm & 1;
  int b = bu / cU1;
  int t0 = thalf * 128;

  float dj[8];
  const float4* dp = (const float4*)(dmatb + (size_t)bu * cJ + lane * 8);
  float4 dA = dp[0], dB = dp[1];
  dj[0] = dA.x; dj[1] = dA.y; dj[2] = dA.z; dj[3] = dA.w;
  dj[4] = dB.x; dj[5] = dB.y; dj[6] = dB.z; dj[7] = dB.w;

  const float* erow0 = e + ((size_t)(b * cT + t0)) * cJ + lane * 8;
  uchar_t* outb = Hbf8 + (size_t)bm * 65536 + lane * 16;

  for (int mg = 0; mg < 8; mg++){
#pragma unroll
    for (int rr = 0; rr < 4; rr++){
      int rloc = wid * 4 + rr;
      const float* ep = erow0 + ((size_t)(mg * 16 + rloc)) * cJ;
      float4 e0 = *(const float4*)ep;
      float4 e1 = *(const float4*)(ep + 4);
      int v0 = pk8(tanh_fast(e0.x + dj[0]), tanh_fast(e0.y + dj[1]),
                   tanh_fast(e0.z + dj[2]), tanh_fast(e0.w + dj[3]));
      int v1 = pk8(tanh_fast(e1.x + dj[4]), tanh_fast(e1.y + dj[5]),
                   tanh_fast(e1.z + dj[6]), tanh_fast(e1.w + dj[7]));
      uint2 pk; pk.x = (unsigned)v0; pk.y = (unsigned)v1;
      *(uint2*)(sH + rloc * 520 + lane * 8) = pk;
    }
    __syncthreads();
#pragma unroll
    for (int q = 0; q < 2; q++){
      int ksp = wid * 2 + q;
      uint2 lo = *(const uint2*)(sH + c16 * 520 + ksp * 64 + quad * 8);
      uint2 hi = *(const uint2*)(sH + c16 * 520 + ksp * 64 + 32 + quad * 8);
      uint4 pack; pack.x = lo.x; pack.y = lo.y; pack.z = hi.x; pack.w = hi.y;
      *(uint4*)(outb + ((size_t)ksp * 8 + mg) * 1024) = pack;
    }
    __syncthreads();
  }
}

// ------------- joint GEMM fp8, double-buffered LDS staging -------------
// 1-D grid 2080: bm=(bid>>5)*8+(bid&7), bn=(bid>>3)&3 (XCD-coherent Hbf reuse).
// Per ksp: stage A(8KB)+B(16KB) once per block via global_load_lds (halves L2
// traffic vs per-wave register loads: A/B were each read 2x redundantly).
// LDS 48KB -> 3 blocks/CU.
__global__ __launch_bounds__(256, 3) void k_joint(
    const uchar_t* __restrict__ Hbf8, const uchar_t* __restrict__ WTf8,
    const float* __restrict__ b_out, const int* __restrict__ targets,
    float* __restrict__ ps,                       // [4][cM]
    float* __restrict__ blank_g, float* __restrict__ lbl_g)
{
  __shared__ uchar_t sAB[2][24576];   // [buf][A 8KB | B 16KB]
  __shared__ float redS[2][128];

  int tid = threadIdx.x;
  int wid = tid >> 6, lane = tid & 63;
  int quad = lane >> 4, c16 = lane & 15;
  int wm = wid & 1, wn = wid >> 1;
  int bid = blockIdx.x;
  int bm = ((bid >> 5) << 3) + (bid & 7);
  int bn = (bid >> 3) & 3;
  int bu = bm >> 1, thalf = bm & 1;
  int b = bu / cU1, u = bu - b * cU1;
  int tg = (u < cU) ? targets[b * cU + u] : -1;
  int lin0 = bu * cT + thalf * 128;    // (b,u,t)-linear base

  const uchar_t* aG = Hbf8 + (size_t)bm * 65536;
  const uchar_t* bG = WTf8 + (size_t)bn * 131072;

  f32x4 acc[4][8];
#pragma unroll
  for (int i = 0; i < 4; i++)
#pragma unroll
    for (int j = 0; j < 8; j++)
      acc[i][j] = (f32x4){0.f, 0.f, 0.f, 0.f};

  // stage ksp's fragment chunk into buf (lane-contiguous, wave-uniform base)
  auto stage = [&](int ksp, int buf){
    const uchar_t* a = aG + (size_t)ksp * 8192;
    const uchar_t* bp = bG + (size_t)ksp * 16384;
    uchar_t* d = sAB[buf];
    int o = tid * 16;
    gload16(a + o,            d + o);
    gload16(a + 4096 + o,     d + 4096 + o);
    gload16(bp + o,           d + 8192 + o);
    gload16(bp + 4096 + o,    d + 12288 + o);
    gload16(bp + 8192 + o,    d + 16384 + o);
    gload16(bp + 12288 + o,   d + 20480 + o);
  };

  stage(0, 0);

  const int aOff = wm * 4096 + lane * 16;
  const int bOff = 8192 + wn * 8192 + lane * 16;

#pragma unroll
  for (int ksp = 0; ksp < 8; ksp++){
    int buf = ksp & 1;
    __syncthreads();                    // staging of buf complete (vmcnt drain)
    if (ksp < 7) stage(ksp + 1, buf ^ 1);
    const uchar_t* aL = sAB[buf] + aOff;
    const uchar_t* bL = sAB[buf] + bOff;
    v2i64 af[4], bf[8];
#pragma unroll
    for (int mt = 0; mt < 4; mt++) af[mt] = *(const v2i64*)(aL + mt * 1024);
#pragma unroll
    for (int nt = 0; nt < 8; nt++) bf[nt] = *(const v2i64*)(bL + nt * 1024);
#pragma unroll
    for (int h = 0; h < 2; h++)
#pragma unroll
      for (int mt = 0; mt < 4; mt++)
#pragma unroll
        for (int nt = 0; nt < 8; nt++)
          acc[mt][nt] = __builtin_amdgcn_mfma_f32_16x16x32_fp8_fp8(af[mt][h], bf[nt][h], acc[mt][nt], 0, 0, 0);
    __syncthreads();                    // all reads of buf done before overwrite
  }

  float bv[8];
#pragma unroll
  for (int nt = 0; nt < 8; nt++) bv[nt] = b_out[bn * 256 + (wn * 8 + nt) * 16 + c16];

  bool ownL = (tg >= 0) && ((tg >> 8) == bn) && ((((tg >> 4) & 15) >> 3) == wn);
  int ntO = (tg >> 4) & 7;
  int tgc = tg & 15;
  const float descale = 1.f / 32.f;     // undo the *32 on W_out fp8

#pragma unroll
  for (int mt = 0; mt < 4; mt++){
#pragma unroll
    for (int r = 0; r < 4; r++){
      int rl = wm * 64 + mt * 16 + quad * 4 + r;  // C/D: col=lane&15, row=quad*4+reg (m89)
      float l[8];
#pragma unroll
      for (int nt = 0; nt < 8; nt++) l[nt] = fmaf(acc[mt][nt][r], descale, bv[nt]);
      if (bn == 0 && wn == 0 && c16 == 0) blank_g[lin0 + rl] = l[0];
      if (ownL && c16 == tgc){
        float v = l[0];
#pragma unroll
        for (int k = 1; k < 8; k++) v = (ntO == k) ? l[k] : v;
        lbl_g[lin0 + rl] = v;
      }
      float s = 0.f;
#pragma unroll
      for (int nt = 0; nt < 8; nt++) s += __expf(l[nt]);
      s += __shfl_xor(s, 1, 64);
      s += __shfl_xor(s, 2, 64);
      s += __shfl_xor(s, 4, 64);
      s += __shfl_xor(s, 8, 64);
      if (c16 == 0) redS[wn][rl] = s;
    }
  }
  __syncthreads();
  if (tid < 128)
    ps[(size_t)bn * cM + lin0 + tid] = redS[0][tid] + redS[1][tid];
}

// ------------- RNN-T alpha DP, (u,t) LDS layout: diagonal reads conflict-free -------------
__global__ __launch_bounds__(256) void k_dp(
    const float* __restrict__ blank_g, const float* __restrict__ lbl_g,
    const float* __restrict__ ps,
    const int* __restrict__ in_len, const int* __restrict__ tgt_len,
    float* __restrict__ afin)
{
  __shared__ float sbb[cTU];   // 65 KB
  __shared__ float slb[cTU];   // 65 KB
  int b = blockIdx.x;
  size_t base = (size_t)b * cTU;
  for (int i = threadIdx.x; i < cTU; i += 256){
    size_t g = base + i;
    float S = ps[g] + ps[(size_t)cM + g] + ps[(size_t)2 * cM + g] + ps[(size_t)3 * cM + g];
    float lse = __logf(S);
    sbb[i] = blank_g[g] - lse;
    slb[i] = ((i >> 8) < cU) ? (lbl_g[g] - lse) : NEGF;
  }
  __syncthreads();
  if (threadIdx.x >= 64) return;

  int u = threadIdx.x;                 // 0..63
  int til = in_len[b] - 1;
  int tl  = tgt_len[b];                // 32..64
  float Dprev = (u == 0) ? 0.f : NEGF; // D_d[u] = alpha[d-u][u]
  float D64prev = NEGF;
  bool cap64 = (tl == 64);
  int ub = u << 8;
  int ubm1 = (u - 1) << 8;

  auto loadB = [&](int d) -> float {
    int tb = d - 1 - u;
    bool v = (tb >= 0) & (tb <= cT - 1);
    float x = sbb[ub + (v ? tb : 0)];
    return v ? x : NEGF;
  };
  auto loadL = [&](int d) -> float {
    int t = d - u;
    bool v = (u >= 1) & (t >= 0) & (t <= cT - 1) & ((u - 1) < tl);
    float x = slb[(v ? ubm1 : 0) + (v ? t : 0)];
    return v ? x : NEGF;
  };

  float blv = loadB(1), lvv = loadL(1);
  for (int d = 1; d <= 319; d++){
    float blv_c = blv, lvv_c = lvv;
    blv = loadB(d + 1);
    lvv = loadL(d + 1);
    int t = d - u;
    bool tv = (t >= 0) & (t <= cT - 1);
    float up = __shfl_up(Dprev, 1, 64);
    float term1 = Dprev + blv_c;
    float term2 = up + lvv_c;
    float Dcur = tv ? logadd(term1, term2) : NEGF;
    if (u == tl && t == til)
      afin[b] = Dcur + sbb[ub + til];
    if (cap64){
      int t64 = d - 64;
      if (t64 >= 0 && t64 <= cT - 1){
        float s63 = __shfl(Dprev, 63, 64);
        float b64v = (t64 >= 1) ? sbb[(cU << 8) + (t64 - 1)] : NEGF;
        float tA = (t64 >= 1) ? (D64prev + b64v) : NEGF;
        float tB = s63 + slb[((cU - 1) << 8) + t64];
        float D64 = logadd(tA, tB);
        if (t64 == til && u == 0)
          afin[b] = D64 + sbb[(cU << 8) + til];
        D64prev = D64;
      }
    }
    Dprev = Dcur;
  }
}

__global__ void k_final(const float* __restrict__ afin, float* __restrict__ out){
  if (threadIdx.x == 0)
    out[0] = -0.25f * (afin[0] + afin[1] + afin[2] + afin[3]);
}

extern "C" void kernel_launch(void* const* d_in, const int* in_sizes, int n_in,
                              void* d_out, int out_size, void* d_ws, size_t ws_size,
                              hipStream_t stream)
{
  (void)in_sizes; (void)n_in; (void)out_size; (void)ws_size;
  const float* inputs = (const float*)d_in[0];   // (4,256,80)
  const float* W_enc  = (const float*)d_in[1];   // (80,512)
  const float* emb    = (const float*)d_in[2];   // (1024,512)
  const float* W_jenc = (const float*)d_in[3];   // (512,512)
  const float* W_jdec = (const float*)d_in[4];   // (512,512)
  const float* b_j    = (const float*)d_in[5];   // (512)
  const float* W_out  = (const float*)d_in[6];   // (512,1024)
  const float* b_out  = (const float*)d_in[7];   // (1024)
  const int* targets  = (const int*)d_in[8];     // (4,64)
  const int* in_len   = (const int*)d_in[9];     // (4)
  const int* tgt_len  = (const int*)d_in[10];    // (4)

  char* w = (char*)d_ws;
  auto alloc = [&](size_t bytes){ char* p = w; w += (bytes + 255) & ~(size_t)255; return p; };
  float* Wcomb   = (float*)alloc((size_t)80 * 512 * 4);
  float* e       = (float*)alloc((size_t)1024 * 512 * 4);
  float* dmatb   = (float*)alloc((size_t)260 * 512 * 4);
  float* blank_g = (float*)alloc((size_t)cM * 4);
  float* lbl_g   = (float*)alloc((size_t)cM * 4);
  float* ps      = (float*)alloc((size_t)4 * cM * 4);
  float* afin    = (float*)alloc(256);
  uchar_t* Hbf8  = (uchar_t*)alloc((size_t)520 * 65536);
  uchar_t* WTf8  = (uchar_t*)alloc((size_t)4 * 131072);

  k_pre<<<202, 256, 0, stream>>>(W_enc, W_jenc, Wcomb, emb, targets, W_jdec, b_j, dmatb,
                                 W_out, WTf8);
  k_gemm_e<<<dim3(2, 256), 256, 0, stream>>>(inputs, Wcomb, e);
  k_hf<<<520, 256, 0, stream>>>(e, dmatb, Hbf8);
  k_joint<<<2080, 256, 0, stream>>>(Hbf8, WTf8, b_out, targets, ps, blank_g, lbl_g);
  k_dp<<<4, 256, 0, stream>>>(blank_g, lbl_g, ps, in_len, tgt_len, afin);
  k_final<<<1, 64, 0, stream>>>(afin, (float*)d_out);
}

// Round 9
// 330.764 us; speedup vs baseline: 1.0366x; 1.0366x over previous
//
#include <hip/hip_runtime.h>
#include <stdint.h>

#define NEGF (-1e30f)

typedef unsigned short ushort_t;
typedef unsigned char uchar_t;
typedef __attribute__((ext_vector_type(2))) long v2i64;
typedef __attribute__((ext_vector_type(4))) float f32x4;

constexpr int cB = 4, cT = 256, cU = 64, cU1 = 65, cV = 1024, cF = 80, cH = 512, cJ = 512;
constexpr int cM = cB * cT * cU1; // 66560
constexpr int cTU = cT * cU1;     // 16640 (per-batch (u,t) plane: u*256+t)
constexpr int cD = 320;           // diagonals t+u: 0..319
constexpr int cDS = 66;           // diagonal plane stride (u index 0..64, pad)

// Padé(2,2) tanh + clamp: max err ~0.016, far below fp8-e4m3 half-step; no v_exp.
__device__ __forceinline__ float tanh_fast(float x){
  float t = x * x;
  float num = x * (27.f + t);
  float den = fmaf(9.f, t, 27.f);
  float r = num * __builtin_amdgcn_rcpf(den);
  return fminf(1.f, fmaxf(-1.f, r));
}

__device__ __forceinline__ float logadd(float x, float y){
  float m = fmaxf(x, y);
  return m + __logf(1.f + __expf(-fabsf(x - y)));
}

__device__ __forceinline__ int pk8(float a, float b, float c, float d){
  int v = __builtin_amdgcn_cvt_pk_fp8_f32(a, b, 0, false);
  v = __builtin_amdgcn_cvt_pk_fp8_f32(c, d, v, true);
  return v;
}

__device__ __forceinline__ void gload16(const void* g, void* l){
  __builtin_amdgcn_global_load_lds(
      (__attribute__((address_space(1))) void*)(g),
      (__attribute__((address_space(3))) void*)(l), 16, 0, 0);
}

// ------------- fused prologue: 3 independent jobs in one dispatch -------------
// bid 0..39   : Wcomb(80,512)  = W_enc @ W_jenc
// bid 40..169 : dmatb(260,512) = emb[padded] @ W_jdec + b_j
// bid 170..201: WTf8 fp8 fragment-order transpose of 32*W_out (2-ks-packed)
__global__ __launch_bounds__(256) void k_pre(
    const float* __restrict__ W_enc, const float* __restrict__ W_jenc,
    float* __restrict__ Wcomb,
    const float* __restrict__ emb, const int* __restrict__ targets,
    const float* __restrict__ W_jdec, const float* __restrict__ b_j,
    float* __restrict__ dmatb,
    const float* __restrict__ W_out, uchar_t* __restrict__ WTf8)
{
  __shared__ float sA[4][512];
  int bid = blockIdx.x;
  int tid = threadIdx.x;

  if (bid < 170){
    bool isW = (bid < 40);
    int id = isW ? bid : bid - 40;
    int bx = id & 1, by = id >> 1;
    int m0 = by * 4;
    int col = bx * 256 + tid;
    const float* Bm = isW ? W_jenc : W_jdec;
    for (int i = tid; i < 4 * 512; i += 256){
      int r = i >> 9, c = i & 511;
      if (isW){
        sA[r][c] = W_enc[(size_t)(m0 + r) * 512 + c];
      } else {
        int row = m0 + r;
        int b = row / cU1, u = row % cU1;
        int src = (u == 0) ? 0 : targets[b * cU + (u - 1)];
        sA[r][c] = emb[(size_t)src * cH + c];
      }
    }
    __syncthreads();
    float a0 = 0.f, a1 = 0.f, a2 = 0.f, a3 = 0.f;
#pragma unroll 8
    for (int k = 0; k < 512; k++){
      float bv = Bm[(size_t)k * cJ + col];
      a0 = fmaf(sA[0][k], bv, a0);
      a1 = fmaf(sA[1][k], bv, a1);
      a2 = fmaf(sA[2][k], bv, a2);
      a3 = fmaf(sA[3][k], bv, a3);
    }
    float bb = isW ? 0.f : b_j[col];
    float* C = isW ? Wcomb : dmatb;
    C[(size_t)(m0 + 0) * cJ + col] = a0 + bb;
    C[(size_t)(m0 + 1) * cJ + col] = a1 + bb;
    C[(size_t)(m0 + 2) * cJ + col] = a2 + bb;
    C[(size_t)(m0 + 3) * cJ + col] = a3 + bb;
  } else {
    // WTf8[((bn*8+ksp)*16 + nt16)*1024 + lane*16]: 16 B = frag(ks=2ksp) || frag(ks=2ksp+1)
    int id = bid - 170;                  // 0..31
    int bn = id & 3, ksp = id >> 2;      // ksp 0..7
    int lane = tid & 63, nth = tid >> 6;
    int c16 = lane & 15, quad = lane >> 4;
    int jA = ksp * 64 + quad * 8;
#pragma unroll
    for (int i = 0; i < 4; i++){
      int nt16 = nth * 4 + i;
      int n = bn * 256 + nt16 * 16 + c16;
      unsigned int p[4];
#pragma unroll
      for (int h = 0; h < 4; h++){
        int j0 = jA + (h >> 1) * 32 + (h & 1) * 4;
        float w0 = W_out[(size_t)(j0 + 0) * cV + n] * 32.f;
        float w1 = W_out[(size_t)(j0 + 1) * cV + n] * 32.f;
        float w2 = W_out[(size_t)(j0 + 2) * cV + n] * 32.f;
        float w3 = W_out[(size_t)(j0 + 3) * cV + n] * 32.f;
        p[h] = (unsigned)pk8(w0, w1, w2, w3);
      }
      uint4 pack; pack.x = p[0]; pack.y = p[1]; pack.z = p[2]; pack.w = p[3];
      *(uint4*)(WTf8 + (((size_t)(bn * 8 + ksp) * 16 + nt16) * 64 + lane) * 16) = pack;
    }
  }
}

// ------------- e = inputs @ Wcomb  (K=80), 4 rows/block -------------
__global__ void k_gemm_e(const float* __restrict__ A, const float* __restrict__ Bm,
                         float* __restrict__ C){
  __shared__ float sA[4][80];
  int m0 = blockIdx.y * 4;
  int col = blockIdx.x * 256 + threadIdx.x;
  for (int i = threadIdx.x; i < 4 * 80; i += 256)
    sA[i / 80][i % 80] = A[(size_t)(m0 + i / 80) * 80 + (i % 80)];
  __syncthreads();
  float a0 = 0.f, a1 = 0.f, a2 = 0.f, a3 = 0.f;
#pragma unroll 8
  for (int k = 0; k < 80; k++){
    float bv = Bm[(size_t)k * cJ + col];
    a0 = fmaf(sA[0][k], bv, a0);
    a1 = fmaf(sA[1][k], bv, a1);
    a2 = fmaf(sA[2][k], bv, a2);
    a3 = fmaf(sA[3][k], bv, a3);
  }
  C[(size_t)(m0 + 0) * cJ + col] = a0;
  C[(size_t)(m0 + 1) * cJ + col] = a1;
  C[(size_t)(m0 + 2) * cJ + col] = a2;
  C[(size_t)(m0 + 3) * cJ + col] = a3;
}

// ------------- H fp8 fragment-order, t-minor, coalesced via LDS bounce -------------
__global__ __launch_bounds__(256) void k_hf(const float* __restrict__ e,
                                            const float* __restrict__ dmatb,
                                            uchar_t* __restrict__ Hbf8){
  __shared__ uchar_t sH[16 * 520];    // 16 rows x 512 B, pad 8 B
  int tid = threadIdx.x;
  int wid = tid >> 6, lane = tid & 63;
  int c16 = lane & 15, quad = lane >> 4;
  int bm = blockIdx.x;
  int bu = bm >> 1, thalf = bm & 1;
  int b = bu / cU1;
  int t0 = thalf * 128;

  float dj[8];
  const float4* dp = (const float4*)(dmatb + (size_t)bu * cJ + lane * 8);
  float4 dA = dp[0], dB = dp[1];
  dj[0] = dA.x; dj[1] = dA.y; dj[2] = dA.z; dj[3] = dA.w;
  dj[4] = dB.x; dj[5] = dB.y; dj[6] = dB.z; dj[7] = dB.w;

  const float* erow0 = e + ((size_t)(b * cT + t0)) * cJ + lane * 8;
  uchar_t* outb = Hbf8 + (size_t)bm * 65536 + lane * 16;

  for (int mg = 0; mg < 8; mg++){
#pragma unroll
    for (int rr = 0; rr < 4; rr++){
      int rloc = wid * 4 + rr;
      const float* ep = erow0 + ((size_t)(mg * 16 + rloc)) * cJ;
      float4 e0 = *(const float4*)ep;
      float4 e1 = *(const float4*)(ep + 4);
      int v0 = pk8(tanh_fast(e0.x + dj[0]), tanh_fast(e0.y + dj[1]),
                   tanh_fast(e0.z + dj[2]), tanh_fast(e0.w + dj[3]));
      int v1 = pk8(tanh_fast(e1.x + dj[4]), tanh_fast(e1.y + dj[5]),
                   tanh_fast(e1.z + dj[6]), tanh_fast(e1.w + dj[7]));
      uint2 pk; pk.x = (unsigned)v0; pk.y = (unsigned)v1;
      *(uint2*)(sH + rloc * 520 + lane * 8) = pk;
    }
    __syncthreads();
#pragma unroll
    for (int q = 0; q < 2; q++){
      int ksp = wid * 2 + q;
      uint2 lo = *(const uint2*)(sH + c16 * 520 + ksp * 64 + quad * 8);
      uint2 hi = *(const uint2*)(sH + c16 * 520 + ksp * 64 + 32 + quad * 8);
      uint4 pack; pack.x = lo.x; pack.y = lo.y; pack.z = hi.x; pack.w = hi.y;
      *(uint4*)(outb + ((size_t)ksp * 8 + mg) * 1024) = pack;
    }
    __syncthreads();
  }
}

// ------------- joint GEMM fp8, double-buffered LDS staging -------------
// Round-7 structure (functionally verified) with __launch_bounds__(256,2):
// (256,3) capped unified regs at ~170 < 128 acc + ~85 VGPR -> accumulator spill
// (WRITE_SIZE 386 MB of scratch). At 2 waves/EU the ~213-reg budget fits.
__global__ __launch_bounds__(256, 2) void k_joint(
    const uchar_t* __restrict__ Hbf8, const uchar_t* __restrict__ WTf8,
    const float* __restrict__ b_out, const int* __restrict__ targets,
    float* __restrict__ ps,                       // [4][cM]
    float* __restrict__ blank_g, float* __restrict__ lbl_g)
{
  __shared__ uchar_t sAB[2][24576];   // [buf][A 8KB | B 16KB]
  __shared__ float redS[2][128];

  int tid = threadIdx.x;
  int wid = tid >> 6, lane = tid & 63;
  int quad = lane >> 4, c16 = lane & 15;
  int wm = wid & 1, wn = wid >> 1;
  int bid = blockIdx.x;
  int bm = ((bid >> 5) << 3) + (bid & 7);
  int bn = (bid >> 3) & 3;
  int bu = bm >> 1, thalf = bm & 1;
  int b = bu / cU1, u = bu - b * cU1;
  int tg = (u < cU) ? targets[b * cU + u] : -1;
  int lin0 = bu * cT + thalf * 128;    // (b,u,t)-linear base

  const uchar_t* aG = Hbf8 + (size_t)bm * 65536;
  const uchar_t* bG = WTf8 + (size_t)bn * 131072;

  f32x4 acc[4][8];
#pragma unroll
  for (int i = 0; i < 4; i++)
#pragma unroll
    for (int j = 0; j < 8; j++)
      acc[i][j] = (f32x4){0.f, 0.f, 0.f, 0.f};

  auto stage = [&](int ksp, int buf){
    const uchar_t* a = aG + (size_t)ksp * 8192;
    const uchar_t* bp = bG + (size_t)ksp * 16384;
    uchar_t* d = sAB[buf];
    int o = tid * 16;
    gload16(a + o,            d + o);
    gload16(a + 4096 + o,     d + 4096 + o);
    gload16(bp + o,           d + 8192 + o);
    gload16(bp + 4096 + o,    d + 12288 + o);
    gload16(bp + 8192 + o,    d + 16384 + o);
    gload16(bp + 12288 + o,   d + 20480 + o);
  };

  stage(0, 0);

  const int aOff = wm * 4096 + lane * 16;
  const int bOff = 8192 + wn * 8192 + lane * 16;

#pragma unroll
  for (int ksp = 0; ksp < 8; ksp++){
    int buf = ksp & 1;
    __syncthreads();                    // staging of buf complete
    if (ksp < 7) stage(ksp + 1, buf ^ 1);
    const uchar_t* aL = sAB[buf] + aOff;
    const uchar_t* bL = sAB[buf] + bOff;
    v2i64 af[4], bf[8];
#pragma unroll
    for (int mt = 0; mt < 4; mt++) af[mt] = *(const v2i64*)(aL + mt * 1024);
#pragma unroll
    for (int nt = 0; nt < 8; nt++) bf[nt] = *(const v2i64*)(bL + nt * 1024);
#pragma unroll
    for (int h = 0; h < 2; h++)
#pragma unroll
      for (int mt = 0; mt < 4; mt++)
#pragma unroll
        for (int nt = 0; nt < 8; nt++)
          acc[mt][nt] = __builtin_amdgcn_mfma_f32_16x16x32_fp8_fp8(af[mt][h], bf[nt][h], acc[mt][nt], 0, 0, 0);
    __syncthreads();                    // all reads of buf done before overwrite
  }

  float bv[8];
#pragma unroll
  for (int nt = 0; nt < 8; nt++) bv[nt] = b_out[bn * 256 + (wn * 8 + nt) * 16 + c16];

  bool ownL = (tg >= 0) && ((tg >> 8) == bn) && ((((tg >> 4) & 15) >> 3) == wn);
  int ntO = (tg >> 4) & 7;
  int tgc = tg & 15;
  const float descale = 1.f / 32.f;     // undo the *32 on W_out fp8

#pragma unroll
  for (int mt = 0; mt < 4; mt++){
#pragma unroll
    for (int r = 0; r < 4; r++){
      int rl = wm * 64 + mt * 16 + quad * 4 + r;  // C/D: col=lane&15, row=quad*4+reg (m89)
      float l[8];
#pragma unroll
      for (int nt = 0; nt < 8; nt++) l[nt] = fmaf(acc[mt][nt][r], descale, bv[nt]);
      if (bn == 0 && wn == 0 && c16 == 0) blank_g[lin0 + rl] = l[0];
      if (ownL && c16 == tgc){
        float v = l[0];
#pragma unroll
        for (int k = 1; k < 8; k++) v = (ntO == k) ? l[k] : v;
        lbl_g[lin0 + rl] = v;
      }
      float s = 0.f;
#pragma unroll
      for (int nt = 0; nt < 8; nt++) s += __expf(l[nt]);
      s += __shfl_xor(s, 1, 64);
      s += __shfl_xor(s, 2, 64);
      s += __shfl_xor(s, 4, 64);
      s += __shfl_xor(s, 8, 64);
      if (c16 == 0) redS[wn][rl] = s;
    }
  }
  __syncthreads();
  if (tid < 128)
    ps[(size_t)bn * cM + lin0 + tid] = redS[0][tid] + redS[1][tid];
}

// ------------- lse merge -> diagonal-major DP operands -------------
// cell (b,u,t) -> blankd/lbld[b][t+u][u]. Reads coalesced; scattered dword
// stores (~130K lines) are cheap. lbld only for u<64 (u=64 has no label).
__global__ __launch_bounds__(256) void k_lse(
    const float* __restrict__ ps, const float* __restrict__ blank_g,
    const float* __restrict__ lbl_g,
    float* __restrict__ blankd, float* __restrict__ lbld)
{
  int cell = blockIdx.x * 256 + threadIdx.x;   // 66560 = 260*256
  int b = cell / cTU;
  int r = cell - b * cTU;
  int u = r >> 8, t = r & 255;
  float S = ps[cell] + ps[(size_t)cM + cell] + ps[(size_t)2 * cM + cell] + ps[(size_t)3 * cM + cell];
  float lse = __logf(S);
  int idx = (b * cD + t + u) * cDS + u;
  blankd[idx] = blank_g[cell] - lse;
  if (u < cU) lbld[idx] = lbl_g[cell] - lse;
}

// ------------- RNN-T alpha DP on diagonal planes + final reduce, 1 block -------------
// wave w = batch. DP step d reads only plane d-1 (coalesced, lane=u); u-1 values
// via shfl_up. 8-deep register prefetch groups hide global latency.
__global__ __launch_bounds__(256) void k_dpf(
    const float* __restrict__ blankd, const float* __restrict__ lbld,
    const int* __restrict__ in_len, const int* __restrict__ tgt_len,
    float* __restrict__ out)
{
  __shared__ float s_res[4];
  int tid = threadIdx.x;
  int wid = tid >> 6, u = tid & 63;
  int b = wid;
  int til = in_len[b] - 1;
  int tl  = tgt_len[b];
  bool cap64 = (tl == 64);
  const float* pb_b = blankd + (size_t)b * cD * cDS;
  const float* pl_b = lbld   + (size_t)b * cD * cDS;
  float fb   = pb_b[(til + tl) * cDS + tl];    // blank at (t=til, u=tl)
  float fb64 = pb_b[(til + 64) * cDS + 64];

  float res = 0.f;
  float Dprev = (u == 0) ? 0.f : NEGF;
  float D64prev = NEGF;

  float rb[2][8], rl[2][8], r64[2][8];
  auto loadg = [&](int g, int s){
#pragma unroll
    for (int j = 0; j < 8; j++){
      int p = g * 8 + j;                       // plane index (d-1)
      if (p <= 318){
        const float* bp = pb_b + p * cDS;
        rb[s][j]  = bp[u];
        rl[s][j]  = pl_b[p * cDS + u];
        r64[s][j] = bp[64];
      } else {
        rb[s][j] = NEGF; rl[s][j] = NEGF; r64[s][j] = NEGF;
      }
    }
  };
  loadg(0, 0);

  for (int g = 0; g < 40; g++){
    int s = g & 1;
    if (g < 39) loadg(g + 1, s ^ 1);
#pragma unroll
    for (int j = 0; j < 8; j++){
      int d = g * 8 + 1 + j;
      if (d <= 319){
        float pb = rb[s][j], pl = rl[s][j], p64 = r64[s][j];
        int t = d - u;
        bool tv  = (t >= 0) & (t <= cT - 1);
        bool t1v = (t >= 1) & (t <= cT - 1);
        float blv = t1v ? pb : NEGF;
        float plm1 = __shfl_up(pl, 1, 64);
        bool lval = (u >= 1) & tv & ((u - 1) < tl);
        float lvv = lval ? plm1 : NEGF;
        float up = __shfl_up(Dprev, 1, 64);
        float term1 = Dprev + blv;
        float term2 = up + lvv;
        float Dcur = tv ? logadd(term1, term2) : NEGF;
        if (u == tl && t == til) res = Dcur + fb;
        if (cap64){
          int t64 = d - 64;
          if (t64 >= 0 && t64 <= cT - 1){
            float s63 = __shfl(Dprev, 63, 64);
            float l63 = __shfl(pl, 63, 64);
            float b64v = (t64 >= 1) ? p64 : NEGF;
            float tA = (t64 >= 1) ? (D64prev + b64v) : NEGF;
            float tB = s63 + l63;
            float D64 = logadd(tA, tB);
            if (t64 == til && u == 0) res = D64 + fb64;
            D64prev = D64;
          }
        }
        Dprev = Dcur;
      }
    }
  }

  // exactly one lane per wave holds res != 0 (the hit); butterfly-sum broadcasts it
  res += __shfl_xor(res, 1, 64);
  res += __shfl_xor(res, 2, 64);
  res += __shfl_xor(res, 4, 64);
  res += __shfl_xor(res, 8, 64);
  res += __shfl_xor(res, 16, 64);
  res += __shfl_xor(res, 32, 64);
  if (u == 0) s_res[wid] = res;
  __syncthreads();
  if (tid == 0)
    out[0] = -0.25f * (s_res[0] + s_res[1] + s_res[2] + s_res[3]);
}

extern "C" void kernel_launch(void* const* d_in, const int* in_sizes, int n_in,
                              void* d_out, int out_size, void* d_ws, size_t ws_size,
                              hipStream_t stream)
{
  (void)in_sizes; (void)n_in; (void)out_size; (void)ws_size;
  const float* inputs = (const float*)d_in[0];   // (4,256,80)
  const float* W_enc  = (const float*)d_in[1];   // (80,512)
  const float* emb    = (const float*)d_in[2];   // (1024,512)
  const float* W_jenc = (const float*)d_in[3];   // (512,512)
  const float* W_jdec = (const float*)d_in[4];   // (512,512)
  const float* b_j    = (const float*)d_in[5];   // (512)
  const float* W_out  = (const float*)d_in[6];   // (512,1024)
  const float* b_out  = (const float*)d_in[7];   // (1024)
  const int* targets  = (const int*)d_in[8];     // (4,64)
  const int* in_len   = (const int*)d_in[9];     // (4)
  const int* tgt_len  = (const int*)d_in[10];    // (4)

  char* w = (char*)d_ws;
  auto alloc = [&](size_t bytes){ char* p = w; w += (bytes + 255) & ~(size_t)255; return p; };
  float* Wcomb   = (float*)alloc((size_t)80 * 512 * 4);
  float* e       = (float*)alloc((size_t)1024 * 512 * 4);
  float* dmatb   = (float*)alloc((size_t)260 * 512 * 4);
  float* blank_g = (float*)alloc((size_t)cM * 4);
  float* lbl_g   = (float*)alloc((size_t)cM * 4);
  float* ps      = (float*)alloc((size_t)4 * cM * 4);
  float* blankd  = (float*)alloc((size_t)cB * cD * cDS * 4);
  float* lbld    = (float*)alloc((size_t)cB * cD * cDS * 4);
  uchar_t* Hbf8  = (uchar_t*)alloc((size_t)520 * 65536);
  uchar_t* WTf8  = (uchar_t*)alloc((size_t)4 * 131072);

  k_pre<<<202, 256, 0, stream>>>(W_enc, W_jenc, Wcomb, emb, targets, W_jdec, b_j, dmatb,
                                 W_out, WTf8);
  k_gemm_e<<<dim3(2, 256), 256, 0, stream>>>(inputs, Wcomb, e);
  k_hf<<<520, 256, 0, stream>>>(e, dmatb, Hbf8);
  k_joint<<<2080, 256, 0, stream>>>(Hbf8, WTf8, b_out, targets, ps, blank_g, lbl_g);
  k_lse<<<260, 256, 0, stream>>>(ps, blank_g, lbl_g, blankd, lbld);
  k_dpf<<<1, 256, 0, stream>>>(blankd, lbld, in_len, tgt_len, (float*)d_out);
}

// Round 10
// 260.510 us; speedup vs baseline: 1.3162x; 1.2697x over previous
//
#include <hip/hip_runtime.h>
#include <stdint.h>

#define NEGF (-1e30f)

typedef unsigned short ushort_t;
typedef unsigned char uchar_t;
typedef __attribute__((ext_vector_type(2))) long v2i64;
typedef __attribute__((ext_vector_type(4))) float f32x4;

constexpr int cB = 4, cT = 256, cU = 64, cU1 = 65, cV = 1024, cF = 80, cH = 512, cJ = 512;
constexpr int cM = cB * cT * cU1; // 66560
constexpr int cTU = cT * cU1;     // 16640 (per-batch (u,t) plane: u*256+t)

// Padé(2,2) tanh + clamp: max err ~0.016, far below fp8-e4m3 half-step; no v_exp.
__device__ __forceinline__ float tanh_fast(float x){
  float t = x * x;
  float num = x * (27.f + t);
  float den = fmaf(9.f, t, 27.f);
  float r = num * __builtin_amdgcn_rcpf(den);
  return fminf(1.f, fmaxf(-1.f, r));
}

__device__ __forceinline__ float logadd(float x, float y){
  float m = fmaxf(x, y);
  return m + __logf(1.f + __expf(-fabsf(x - y)));
}

__device__ __forceinline__ int pk8(float a, float b, float c, float d){
  int v = __builtin_amdgcn_cvt_pk_fp8_f32(a, b, 0, false);
  v = __builtin_amdgcn_cvt_pk_fp8_f32(c, d, v, true);
  return v;
}

__device__ __forceinline__ void gload16(const void* g, void* l){
  __builtin_amdgcn_global_load_lds(
      (__attribute__((address_space(1))) void*)(g),
      (__attribute__((address_space(3))) void*)(l), 16, 0, 0);
}

// ------------- fused prologue: 3 independent jobs in one dispatch -------------
// bid 0..39   : Wcomb(80,512)  = W_enc @ W_jenc
// bid 40..169 : dmatb(260,512) = emb[padded] @ W_jdec + b_j
// bid 170..201: WTf8 fp8 fragment-order transpose of 32*W_out (2-ks-packed)
__global__ __launch_bounds__(256) void k_pre(
    const float* __restrict__ W_enc, const float* __restrict__ W_jenc,
    float* __restrict__ Wcomb,
    const float* __restrict__ emb, const int* __restrict__ targets,
    const float* __restrict__ W_jdec, const float* __restrict__ b_j,
    float* __restrict__ dmatb,
    const float* __restrict__ W_out, uchar_t* __restrict__ WTf8)
{
  __shared__ float sA[4][512];
  int bid = blockIdx.x;
  int tid = threadIdx.x;

  if (bid < 170){
    bool isW = (bid < 40);
    int id = isW ? bid : bid - 40;
    int bx = id & 1, by = id >> 1;
    int m0 = by * 4;
    int col = bx * 256 + tid;
    const float* Bm = isW ? W_jenc : W_jdec;
    for (int i = tid; i < 4 * 512; i += 256){
      int r = i >> 9, c = i & 511;
      if (isW){
        sA[r][c] = W_enc[(size_t)(m0 + r) * 512 + c];
      } else {
        int row = m0 + r;
        int b = row / cU1, u = row % cU1;
        int src = (u == 0) ? 0 : targets[b * cU + (u - 1)];
        sA[r][c] = emb[(size_t)src * cH + c];
      }
    }
    __syncthreads();
    float a0 = 0.f, a1 = 0.f, a2 = 0.f, a3 = 0.f;
#pragma unroll 8
    for (int k = 0; k < 512; k++){
      float bv = Bm[(size_t)k * cJ + col];
      a0 = fmaf(sA[0][k], bv, a0);
      a1 = fmaf(sA[1][k], bv, a1);
      a2 = fmaf(sA[2][k], bv, a2);
      a3 = fmaf(sA[3][k], bv, a3);
    }
    float bb = isW ? 0.f : b_j[col];
    float* C = isW ? Wcomb : dmatb;
    C[(size_t)(m0 + 0) * cJ + col] = a0 + bb;
    C[(size_t)(m0 + 1) * cJ + col] = a1 + bb;
    C[(size_t)(m0 + 2) * cJ + col] = a2 + bb;
    C[(size_t)(m0 + 3) * cJ + col] = a3 + bb;
  } else {
    // WTf8[((bn*8+ksp)*16 + nt16)*1024 + lane*16]: 16 B = frag(ks=2ksp) || frag(ks=2ksp+1)
    int id = bid - 170;                  // 0..31
    int bn = id & 3, ksp = id >> 2;      // ksp 0..7
    int lane = tid & 63, nth = tid >> 6;
    int c16 = lane & 15, quad = lane >> 4;
    int jA = ksp * 64 + quad * 8;
#pragma unroll
    for (int i = 0; i < 4; i++){
      int nt16 = nth * 4 + i;
      int n = bn * 256 + nt16 * 16 + c16;
      unsigned int p[4];
#pragma unroll
      for (int h = 0; h < 4; h++){
        int j0 = jA + (h >> 1) * 32 + (h & 1) * 4;
        float w0 = W_out[(size_t)(j0 + 0) * cV + n] * 32.f;
        float w1 = W_out[(size_t)(j0 + 1) * cV + n] * 32.f;
        float w2 = W_out[(size_t)(j0 + 2) * cV + n] * 32.f;
        float w3 = W_out[(size_t)(j0 + 3) * cV + n] * 32.f;
        p[h] = (unsigned)pk8(w0, w1, w2, w3);
      }
      uint4 pack; pack.x = p[0]; pack.y = p[1]; pack.z = p[2]; pack.w = p[3];
      *(uint4*)(WTf8 + (((size_t)(bn * 8 + ksp) * 16 + nt16) * 64 + lane) * 16) = pack;
    }
  }
}

// ------------- e = inputs @ Wcomb  (K=80), 4 rows/block -------------
__global__ void k_gemm_e(const float* __restrict__ A, const float* __restrict__ Bm,
                         float* __restrict__ C){
  __shared__ float sA[4][80];
  int m0 = blockIdx.y * 4;
  int col = blockIdx.x * 256 + threadIdx.x;
  for (int i = threadIdx.x; i < 4 * 80; i += 256)
    sA[i / 80][i % 80] = A[(size_t)(m0 + i / 80) * 80 + (i % 80)];
  __syncthreads();
  float a0 = 0.f, a1 = 0.f, a2 = 0.f, a3 = 0.f;
#pragma unroll 8
  for (int k = 0; k < 80; k++){
    float bv = Bm[(size_t)k * cJ + col];
    a0 = fmaf(sA[0][k], bv, a0);
    a1 = fmaf(sA[1][k], bv, a1);
    a2 = fmaf(sA[2][k], bv, a2);
    a3 = fmaf(sA[3][k], bv, a3);
  }
  C[(size_t)(m0 + 0) * cJ + col] = a0;
  C[(size_t)(m0 + 1) * cJ + col] = a1;
  C[(size_t)(m0 + 2) * cJ + col] = a2;
  C[(size_t)(m0 + 3) * cJ + col] = a3;
}

// ------------- H fp8 fragment-order, t-minor, coalesced via LDS bounce -------------
__global__ __launch_bounds__(256) void k_hf(const float* __restrict__ e,
                                            const float* __restrict__ dmatb,
                                            uchar_t* __restrict__ Hbf8){
  __shared__ uchar_t sH[16 * 520];    // 16 rows x 512 B, pad 8 B
  int tid = threadIdx.x;
  int wid = tid >> 6, lane = tid & 63;
  int c16 = lane & 15, quad = lane >> 4;
  int bm = blockIdx.x;
  int bu = bm >> 1, thalf = bm & 1;
  int b = bu / cU1;
  int t0 = thalf * 128;

  float dj[8];
  const float4* dp = (const float4*)(dmatb + (size_t)bu * cJ + lane * 8);
  float4 dA = dp[0], dB = dp[1];
  dj[0] = dA.x; dj[1] = dA.y; dj[2] = dA.z; dj[3] = dA.w;
  dj[4] = dB.x; dj[5] = dB.y; dj[6] = dB.z; dj[7] = dB.w;

  const float* erow0 = e + ((size_t)(b * cT + t0)) * cJ + lane * 8;
  uchar_t* outb = Hbf8 + (size_t)bm * 65536 + lane * 16;

  for (int mg = 0; mg < 8; mg++){
#pragma unroll
    for (int rr = 0; rr < 4; rr++){
      int rloc = wid * 4 + rr;
      const float* ep = erow0 + ((size_t)(mg * 16 + rloc)) * cJ;
      float4 e0 = *(const float4*)ep;
      float4 e1 = *(const float4*)(ep + 4);
      int v0 = pk8(tanh_fast(e0.x + dj[0]), tanh_fast(e0.y + dj[1]),
                   tanh_fast(e0.z + dj[2]), tanh_fast(e0.w + dj[3]));
      int v1 = pk8(tanh_fast(e1.x + dj[4]), tanh_fast(e1.y + dj[5]),
                   tanh_fast(e1.z + dj[6]), tanh_fast(e1.w + dj[7]));
      uint2 pk; pk.x = (unsigned)v0; pk.y = (unsigned)v1;
      *(uint2*)(sH + rloc * 520 + lane * 8) = pk;
    }
    __syncthreads();
#pragma unroll
    for (int q = 0; q < 2; q++){
      int ksp = wid * 2 + q;
      uint2 lo = *(const uint2*)(sH + c16 * 520 + ksp * 64 + quad * 8);
      uint2 hi = *(const uint2*)(sH + c16 * 520 + ksp * 64 + 32 + quad * 8);
      uint4 pack; pack.x = lo.x; pack.y = lo.y; pack.z = hi.x; pack.w = hi.y;
      *(uint4*)(outb + ((size_t)ksp * 8 + mg) * 1024) = pack;
    }
    __syncthreads();
  }
}

// ------------- joint GEMM fp8, double-buffered LDS staging -------------
// __launch_bounds__(256,2): (256,3) caused accumulator scratch-spill (r7,
// WRITE_SIZE 386 MB); at 2 waves/EU the ~213-reg budget fits.
__global__ __launch_bounds__(256, 2) void k_joint(
    const uchar_t* __restrict__ Hbf8, const uchar_t* __restrict__ WTf8,
    const float* __restrict__ b_out, const int* __restrict__ targets,
    float* __restrict__ ps,                       // [4][cM]
    float* __restrict__ blank_g, float* __restrict__ lbl_g)
{
  __shared__ uchar_t sAB[2][24576];   // [buf][A 8KB | B 16KB]
  __shared__ float redS[2][128];

  int tid = threadIdx.x;
  int wid = tid >> 6, lane = tid & 63;
  int quad = lane >> 4, c16 = lane & 15;
  int wm = wid & 1, wn = wid >> 1;
  int bid = blockIdx.x;
  int bm = ((bid >> 5) << 3) + (bid & 7);
  int bn = (bid >> 3) & 3;
  int bu = bm >> 1, thalf = bm & 1;
  int b = bu / cU1, u = bu - b * cU1;
  int tg = (u < cU) ? targets[b * cU + u] : -1;
  int lin0 = bu * cT + thalf * 128;    // (b,u,t)-linear base

  const uchar_t* aG = Hbf8 + (size_t)bm * 65536;
  const uchar_t* bG = WTf8 + (size_t)bn * 131072;

  f32x4 acc[4][8];
#pragma unroll
  for (int i = 0; i < 4; i++)
#pragma unroll
    for (int j = 0; j < 8; j++)
      acc[i][j] = (f32x4){0.f, 0.f, 0.f, 0.f};

  auto stage = [&](int ksp, int buf){
    const uchar_t* a = aG + (size_t)ksp * 8192;
    const uchar_t* bp = bG + (size_t)ksp * 16384;
    uchar_t* d = sAB[buf];
    int o = tid * 16;
    gload16(a + o,            d + o);
    gload16(a + 4096 + o,     d + 4096 + o);
    gload16(bp + o,           d + 8192 + o);
    gload16(bp + 4096 + o,    d + 12288 + o);
    gload16(bp + 8192 + o,    d + 16384 + o);
    gload16(bp + 12288 + o,   d + 20480 + o);
  };

  stage(0, 0);

  const int aOff = wm * 4096 + lane * 16;
  const int bOff = 8192 + wn * 8192 + lane * 16;

#pragma unroll
  for (int ksp = 0; ksp < 8; ksp++){
    int buf = ksp & 1;
    __syncthreads();                    // staging of buf complete
    if (ksp < 7) stage(ksp + 1, buf ^ 1);
    const uchar_t* aL = sAB[buf] + aOff;
    const uchar_t* bL = sAB[buf] + bOff;
    v2i64 af[4], bf[8];
#pragma unroll
    for (int mt = 0; mt < 4; mt++) af[mt] = *(const v2i64*)(aL + mt * 1024);
#pragma unroll
    for (int nt = 0; nt < 8; nt++) bf[nt] = *(const v2i64*)(bL + nt * 1024);
#pragma unroll
    for (int h = 0; h < 2; h++)
#pragma unroll
      for (int mt = 0; mt < 4; mt++)
#pragma unroll
        for (int nt = 0; nt < 8; nt++)
          acc[mt][nt] = __builtin_amdgcn_mfma_f32_16x16x32_fp8_fp8(af[mt][h], bf[nt][h], acc[mt][nt], 0, 0, 0);
    __syncthreads();                    // all reads of buf done before overwrite
  }

  float bv[8];
#pragma unroll
  for (int nt = 0; nt < 8; nt++) bv[nt] = b_out[bn * 256 + (wn * 8 + nt) * 16 + c16];

  bool ownL = (tg >= 0) && ((tg >> 8) == bn) && ((((tg >> 4) & 15) >> 3) == wn);
  int ntO = (tg >> 4) & 7;
  int tgc = tg & 15;
  const float descale = 1.f / 32.f;     // undo the *32 on W_out fp8

#pragma unroll
  for (int mt = 0; mt < 4; mt++){
#pragma unroll
    for (int r = 0; r < 4; r++){
      int rl = wm * 64 + mt * 16 + quad * 4 + r;  // C/D: col=lane&15, row=quad*4+reg (m89)
      float l[8];
#pragma unroll
      for (int nt = 0; nt < 8; nt++) l[nt] = fmaf(acc[mt][nt][r], descale, bv[nt]);
      if (bn == 0 && wn == 0 && c16 == 0) blank_g[lin0 + rl] = l[0];
      if (ownL && c16 == tgc){
        float v = l[0];
#pragma unroll
        for (int k = 1; k < 8; k++) v = (ntO == k) ? l[k] : v;
        lbl_g[lin0 + rl] = v;
      }
      float s = 0.f;
#pragma unroll
      for (int nt = 0; nt < 8; nt++) s += __expf(l[nt]);
      s += __shfl_xor(s, 1, 64);
      s += __shfl_xor(s, 2, 64);
      s += __shfl_xor(s, 4, 64);
      s += __shfl_xor(s, 8, 64);
      if (c16 == 0) redS[wn][rl] = s;
    }
  }
  __syncthreads();
  if (tid < 128)
    ps[(size_t)bn * cM + lin0 + tid] = redS[0][tid] + redS[1][tid];
}

// ------------- RNN-T alpha DP, (u,t) LDS layout (round-6 proven) -------------
// LDS index u*256+t; diagonal stride 255 = -1 mod 32 -> conflict-free.
// Scalar one-step prefetch (NO runtime-indexed arrays -> stays in VGPRs;
// r9's rb[2][8] double-buffer went to scratch and cost 140 us).
__global__ __launch_bounds__(256) void k_dp(
    const float* __restrict__ blank_g, const float* __restrict__ lbl_g,
    const float* __restrict__ ps,
    const int* __restrict__ in_len, const int* __restrict__ tgt_len,
    float* __restrict__ afin)
{
  __shared__ float sbb[cTU];   // 65 KB
  __shared__ float slb[cTU];   // 65 KB
  int b = blockIdx.x;
  size_t base = (size_t)b * cTU;
  for (int i = threadIdx.x; i < cTU; i += 256){
    size_t g = base + i;
    float S = ps[g] + ps[(size_t)cM + g] + ps[(size_t)2 * cM + g] + ps[(size_t)3 * cM + g];
    float lse = __logf(S);
    sbb[i] = blank_g[g] - lse;
    slb[i] = ((i >> 8) < cU) ? (lbl_g[g] - lse) : NEGF;
  }
  __syncthreads();
  if (threadIdx.x >= 64) return;

  int u = threadIdx.x;                 // 0..63
  int til = in_len[b] - 1;
  int tl  = tgt_len[b];                // 32..64
  float Dprev = (u == 0) ? 0.f : NEGF; // D_d[u] = alpha[d-u][u]
  float D64prev = NEGF;
  bool cap64 = (tl == 64);
  int ub = u << 8;
  int ubm1 = (u - 1) << 8;

  auto loadB = [&](int d) -> float {
    int tb = d - 1 - u;
    bool v = (tb >= 0) & (tb <= cT - 1);
    float x = sbb[ub + (v ? tb : 0)];
    return v ? x : NEGF;
  };
  auto loadL = [&](int d) -> float {
    int t = d - u;
    bool v = (u >= 1) & (t >= 0) & (t <= cT - 1) & ((u - 1) < tl);
    float x = slb[(v ? ubm1 : 0) + (v ? t : 0)];
    return v ? x : NEGF;
  };

  float blv = loadB(1), lvv = loadL(1);
  for (int d = 1; d <= 319; d++){
    float blv_c = blv, lvv_c = lvv;
    blv = loadB(d + 1);
    lvv = loadL(d + 1);
    int t = d - u;
    bool tv = (t >= 0) & (t <= cT - 1);
    float up = __shfl_up(Dprev, 1, 64);
    float term1 = Dprev + blv_c;
    float term2 = up + lvv_c;
    float Dcur = tv ? logadd(term1, term2) : NEGF;
    if (u == tl && t == til)
      afin[b] = Dcur + sbb[ub + til];
    if (cap64){
      int t64 = d - 64;
      if (t64 >= 0 && t64 <= cT - 1){
        float s63 = __shfl(Dprev, 63, 64);
        float b64v = (t64 >= 1) ? sbb[(cU << 8) + (t64 - 1)] : NEGF;
        float tA = (t64 >= 1) ? (D64prev + b64v) : NEGF;
        float tB = s63 + slb[((cU - 1) << 8) + t64];
        float D64 = logadd(tA, tB);
        if (t64 == til && u == 0)
          afin[b] = D64 + sbb[(cU << 8) + til];
        D64prev = D64;
      }
    }
    Dprev = Dcur;
  }
}

__global__ void k_final(const float* __restrict__ afin, float* __restrict__ out){
  if (threadIdx.x == 0)
    out[0] = -0.25f * (afin[0] + afin[1] + afin[2] + afin[3]);
}

extern "C" void kernel_launch(void* const* d_in, const int* in_sizes, int n_in,
                              void* d_out, int out_size, void* d_ws, size_t ws_size,
                              hipStream_t stream)
{
  (void)in_sizes; (void)n_in; (void)out_size; (void)ws_size;
  const float* inputs = (const float*)d_in[0];   // (4,256,80)
  const float* W_enc  = (const float*)d_in[1];   // (80,512)
  const float* emb    = (const float*)d_in[2];   // (1024,512)
  const float* W_jenc = (const float*)d_in[3];   // (512,512)
  const float* W_jdec = (const float*)d_in[4];   // (512,512)
  const float* b_j    = (const float*)d_in[5];   // (512)
  const float* W_out  = (const float*)d_in[6];   // (512,1024)
  const float* b_out  = (const float*)d_in[7];   // (1024)
  const int* targets  = (const int*)d_in[8];     // (4,64)
  const int* in_len   = (const int*)d_in[9];     // (4)
  const int* tgt_len  = (const int*)d_in[10];    // (4)

  char* w = (char*)d_ws;
  auto alloc = [&](size_t bytes){ char* p = w; w += (bytes + 255) & ~(size_t)255; return p; };
  float* Wcomb   = (float*)alloc((size_t)80 * 512 * 4);
  float* e       = (float*)alloc((size_t)1024 * 512 * 4);
  float* dmatb   = (float*)alloc((size_t)260 * 512 * 4);
  float* blank_g = (float*)alloc((size_t)cM * 4);
  float* lbl_g   = (float*)alloc((size_t)cM * 4);
  float* ps      = (float*)alloc((size_t)4 * cM * 4);
  float* afin    = (float*)alloc(256);
  uchar_t* Hbf8  = (uchar_t*)alloc((size_t)520 * 65536);
  uchar_t* WTf8  = (uchar_t*)alloc((size_t)4 * 131072);

  k_pre<<<202, 256, 0, stream>>>(W_enc, W_jenc, Wcomb, emb, targets, W_jdec, b_j, dmatb,
                                 W_out, WTf8);
  k_gemm_e<<<dim3(2, 256), 256, 0, stream>>>(inputs, Wcomb, e);
  k_hf<<<520, 256, 0, stream>>>(e, dmatb, Hbf8);
  k_joint<<<2080, 256, 0, stream>>>(Hbf8, WTf8, b_out, targets, ps, blank_g, lbl_g);
  k_dp<<<4, 256, 0, stream>>>(blank_g, lbl_g, ps, in_len, tgt_len, afin);
  k_final<<<1, 64, 0, stream>>>(afin, (float*)d_out);
}

// Round 11
// 255.207 us; speedup vs baseline: 1.3435x; 1.0208x over previous
//
#include <hip/hip_runtime.h>
#include <stdint.h>

#define NEGF (-1e30f)

typedef unsigned short ushort_t;
typedef unsigned char uchar_t;
typedef __attribute__((ext_vector_type(2))) long v2i64;
typedef __attribute__((ext_vector_type(4))) float f32x4;

constexpr int cB = 4, cT = 256, cU = 64, cU1 = 65, cV = 1024, cF = 80, cH = 512, cJ = 512;
constexpr int cM = cB * cT * cU1; // 66560
constexpr int cTU = cT * cU1;     // 16640 (per-batch (u,t) plane: u*256+t)

// Padé(2,2) tanh + clamp: max err ~0.016, far below fp8-e4m3 half-step; no v_exp.
__device__ __forceinline__ float tanh_fast(float x){
  float t = x * x;
  float num = x * (27.f + t);
  float den = fmaf(9.f, t, 27.f);
  float r = num * __builtin_amdgcn_rcpf(den);
  return fminf(1.f, fmaxf(-1.f, r));
}

__device__ __forceinline__ float logadd(float x, float y){
  float m = fmaxf(x, y);
  return m + __logf(1.f + __expf(-fabsf(x - y)));
}

__device__ __forceinline__ int pk8(float a, float b, float c, float d){
  int v = __builtin_amdgcn_cvt_pk_fp8_f32(a, b, 0, false);
  v = __builtin_amdgcn_cvt_pk_fp8_f32(c, d, v, true);
  return v;
}

// ------------- fused prologue: 3 independent jobs in one dispatch -------------
// bid 0..39   : Wcomb(80,512)  = W_enc @ W_jenc
// bid 40..169 : dmatb(260,512) = emb[padded] @ W_jdec + b_j
// bid 170..201: WTf8 fp8 fragment-order transpose of 32*W_out (2-ks-packed)
__global__ __launch_bounds__(256) void k_pre(
    const float* __restrict__ W_enc, const float* __restrict__ W_jenc,
    float* __restrict__ Wcomb,
    const float* __restrict__ emb, const int* __restrict__ targets,
    const float* __restrict__ W_jdec, const float* __restrict__ b_j,
    float* __restrict__ dmatb,
    const float* __restrict__ W_out, uchar_t* __restrict__ WTf8)
{
  __shared__ float sA[4][512];
  int bid = blockIdx.x;
  int tid = threadIdx.x;

  if (bid < 170){
    bool isW = (bid < 40);
    int id = isW ? bid : bid - 40;
    int bx = id & 1, by = id >> 1;
    int m0 = by * 4;
    int col = bx * 256 + tid;
    const float* Bm = isW ? W_jenc : W_jdec;
    for (int i = tid; i < 4 * 512; i += 256){
      int r = i >> 9, c = i & 511;
      if (isW){
        sA[r][c] = W_enc[(size_t)(m0 + r) * 512 + c];
      } else {
        int row = m0 + r;
        int b = row / cU1, u = row % cU1;
        int src = (u == 0) ? 0 : targets[b * cU + (u - 1)];
        sA[r][c] = emb[(size_t)src * cH + c];
      }
    }
    __syncthreads();
    float a0 = 0.f, a1 = 0.f, a2 = 0.f, a3 = 0.f;
#pragma unroll 8
    for (int k = 0; k < 512; k++){
      float bv = Bm[(size_t)k * cJ + col];
      a0 = fmaf(sA[0][k], bv, a0);
      a1 = fmaf(sA[1][k], bv, a1);
      a2 = fmaf(sA[2][k], bv, a2);
      a3 = fmaf(sA[3][k], bv, a3);
    }
    float bb = isW ? 0.f : b_j[col];
    float* C = isW ? Wcomb : dmatb;
    C[(size_t)(m0 + 0) * cJ + col] = a0 + bb;
    C[(size_t)(m0 + 1) * cJ + col] = a1 + bb;
    C[(size_t)(m0 + 2) * cJ + col] = a2 + bb;
    C[(size_t)(m0 + 3) * cJ + col] = a3 + bb;
  } else {
    // WTf8[((bn4*8+ksp)*16 + nt16)*1024 + lane*16]: 16 B = frag(ks=2ksp) || frag(ks=2ksp+1)
    int id = bid - 170;                  // 0..31
    int bn = id & 3, ksp = id >> 2;      // ksp 0..7
    int lane = tid & 63, nth = tid >> 6;
    int c16 = lane & 15, quad = lane >> 4;
    int jA = ksp * 64 + quad * 8;
#pragma unroll
    for (int i = 0; i < 4; i++){
      int nt16 = nth * 4 + i;
      int n = bn * 256 + nt16 * 16 + c16;
      unsigned int p[4];
#pragma unroll
      for (int h = 0; h < 4; h++){
        int j0 = jA + (h >> 1) * 32 + (h & 1) * 4;
        float w0 = W_out[(size_t)(j0 + 0) * cV + n] * 32.f;
        float w1 = W_out[(size_t)(j0 + 1) * cV + n] * 32.f;
        float w2 = W_out[(size_t)(j0 + 2) * cV + n] * 32.f;
        float w3 = W_out[(size_t)(j0 + 3) * cV + n] * 32.f;
        p[h] = (unsigned)pk8(w0, w1, w2, w3);
      }
      uint4 pack; pack.x = p[0]; pack.y = p[1]; pack.z = p[2]; pack.w = p[3];
      *(uint4*)(WTf8 + (((size_t)(bn * 8 + ksp) * 16 + nt16) * 64 + lane) * 16) = pack;
    }
  }
}

// ------------- e = inputs @ Wcomb  (K=80), 4 rows/block -------------
__global__ void k_gemm_e(const float* __restrict__ A, const float* __restrict__ Bm,
                         float* __restrict__ C){
  __shared__ float sA[4][80];
  int m0 = blockIdx.y * 4;
  int col = blockIdx.x * 256 + threadIdx.x;
  for (int i = threadIdx.x; i < 4 * 80; i += 256)
    sA[i / 80][i % 80] = A[(size_t)(m0 + i / 80) * 80 + (i % 80)];
  __syncthreads();
  float a0 = 0.f, a1 = 0.f, a2 = 0.f, a3 = 0.f;
#pragma unroll 8
  for (int k = 0; k < 80; k++){
    float bv = Bm[(size_t)k * cJ + col];
    a0 = fmaf(sA[0][k], bv, a0);
    a1 = fmaf(sA[1][k], bv, a1);
    a2 = fmaf(sA[2][k], bv, a2);
    a3 = fmaf(sA[3][k], bv, a3);
  }
  C[(size_t)(m0 + 0) * cJ + col] = a0;
  C[(size_t)(m0 + 1) * cJ + col] = a1;
  C[(size_t)(m0 + 2) * cJ + col] = a2;
  C[(size_t)(m0 + 3) * cJ + col] = a3;
}

// ------------- H fp8 fragment-order, t-minor, coalesced via LDS bounce -------------
__global__ __launch_bounds__(256) void k_hf(const float* __restrict__ e,
                                            const float* __restrict__ dmatb,
                                            uchar_t* __restrict__ Hbf8){
  __shared__ uchar_t sH[16 * 520];    // 16 rows x 512 B, pad 8 B
  int tid = threadIdx.x;
  int wid = tid >> 6, lane = tid & 63;
  int c16 = lane & 15, quad = lane >> 4;
  int bm = blockIdx.x;
  int bu = bm >> 1, thalf = bm & 1;
  int b = bu / cU1;
  int t0 = thalf * 128;

  float dj[8];
  const float4* dp = (const float4*)(dmatb + (size_t)bu * cJ + lane * 8);
  float4 dA = dp[0], dB = dp[1];
  dj[0] = dA.x; dj[1] = dA.y; dj[2] = dA.z; dj[3] = dA.w;
  dj[4] = dB.x; dj[5] = dB.y; dj[6] = dB.z; dj[7] = dB.w;

  const float* erow0 = e + ((size_t)(b * cT + t0)) * cJ + lane * 8;
  uchar_t* outb = Hbf8 + (size_t)bm * 65536 + lane * 16;

  for (int mg = 0; mg < 8; mg++){
#pragma unroll
    for (int rr = 0; rr < 4; rr++){
      int rloc = wid * 4 + rr;
      const float* ep = erow0 + ((size_t)(mg * 16 + rloc)) * cJ;
      float4 e0 = *(const float4*)ep;
      float4 e1 = *(const float4*)(ep + 4);
      int v0 = pk8(tanh_fast(e0.x + dj[0]), tanh_fast(e0.y + dj[1]),
                   tanh_fast(e0.z + dj[2]), tanh_fast(e0.w + dj[3]));
      int v1 = pk8(tanh_fast(e1.x + dj[4]), tanh_fast(e1.y + dj[5]),
                   tanh_fast(e1.z + dj[6]), tanh_fast(e1.w + dj[7]));
      uint2 pk; pk.x = (unsigned)v0; pk.y = (unsigned)v1;
      *(uint2*)(sH + rloc * 520 + lane * 8) = pk;
    }
    __syncthreads();
#pragma unroll
    for (int q = 0; q < 2; q++){
      int ksp = wid * 2 + q;
      uint2 lo = *(const uint2*)(sH + c16 * 520 + ksp * 64 + quad * 8);
      uint2 hi = *(const uint2*)(sH + c16 * 520 + ksp * 64 + 32 + quad * 8);
      uint4 pack; pack.x = lo.x; pack.y = lo.y; pack.z = hi.x; pack.w = hi.y;
      *(uint4*)(outb + ((size_t)ksp * 8 + mg) * 1024) = pack;
    }
    __syncthreads();
  }
}

// ------------- joint GEMM fp8: 64x64 wave tile, register-direct, 3 blocks/CU -------------
// MFMA floor is 34 us/CU (16640 MFMA x 4.9 cyc); r6/r10 at 2 waves/SIMD stalled at 39%
// MfmaUtil (L2 latency + serial epilogue). acc=64 regs -> ~130 mandatory regs fits the
// (256,3) cap of ~170 without spilling -> 12 waves/CU: latency hiding + epilogue/MFMA
// cross-block overlap (m114). Grid 4160 = 520 bm x 8 bn; swizzle keeps a bm's 8 bn
// on one XCD (delta-8 bids) so Hbf8 re-reads are L2-served (not BW-bound anyway).
__global__ __launch_bounds__(256, 3) void k_joint(
    const uchar_t* __restrict__ Hbf8, const uchar_t* __restrict__ WTf8,
    const float* __restrict__ b_out, const int* __restrict__ targets,
    float* __restrict__ ps,                       // [8][cM]
    float* __restrict__ blank_g, float* __restrict__ lbl_g)
{
  __shared__ float redS[2][128];

  int tid = threadIdx.x;
  int wid = tid >> 6, lane = tid & 63;
  int quad = lane >> 4, c16 = lane & 15;
  int wm = wid & 1, wn = wid >> 1;
  int bid = blockIdx.x;
  int bm = ((bid >> 6) << 3) + (bid & 7);
  int bn = (bid >> 3) & 7;                       // 128-col strip
  int bu = bm >> 1, thalf = bm & 1;
  int b = bu / cU1, u = bu - b * cU1;
  int tg = (u < cU) ? targets[b * cU + u] : -1;
  int lin0 = bu * cT + thalf * 128;              // (b,u,t)-linear base

  f32x4 acc[4][4];
#pragma unroll
  for (int i = 0; i < 4; i++)
#pragma unroll
    for (int j = 0; j < 4; j++)
      acc[i][j] = (f32x4){0.f, 0.f, 0.f, 0.f};

  // A: rows [wm*64,+64) -> mg = wm*4 + mt; layout [bm][ksp][mg][lane][16]
  const uchar_t* aP = Hbf8 + (size_t)bm * 65536 + (wm * 4) * 1024 + lane * 16;
  // B: cols [bn*128 + wn*64 + nt*16): bn4 = bn>>1, nt16 = (bn&1)*8 + wn*4 + nt
  const uchar_t* bP = WTf8 + (size_t)(bn >> 1) * 131072 + ((bn & 1) * 8 + wn * 4) * 1024 + lane * 16;

#pragma unroll
  for (int ksp = 0; ksp < 8; ksp++){
    v2i64 af[4], bf[4];
#pragma unroll
    for (int mt = 0; mt < 4; mt++)
      af[mt] = *(const v2i64*)(aP + (size_t)ksp * 8192 + mt * 1024);
#pragma unroll
    for (int nt = 0; nt < 4; nt++)
      bf[nt] = *(const v2i64*)(bP + (size_t)ksp * 16384 + nt * 1024);
#pragma unroll
    for (int h = 0; h < 2; h++)
#pragma unroll
      for (int mt = 0; mt < 4; mt++)
#pragma unroll
        for (int nt = 0; nt < 4; nt++)
          acc[mt][nt] = __builtin_amdgcn_mfma_f32_16x16x32_fp8_fp8(af[mt][h], bf[nt][h], acc[mt][nt], 0, 0, 0);
  }

  float bv[4];
#pragma unroll
  for (int nt = 0; nt < 4; nt++) bv[nt] = b_out[bn * 128 + (wn * 4 + nt) * 16 + c16];

  bool ownL = (tg >= 0) && ((tg >> 7) == bn) && (((tg >> 6) & 1) == wn);
  int ntO = (tg >> 4) & 3;
  int tgc = tg & 15;
  const float descale = 1.f / 32.f;     // undo the *32 on W_out fp8

#pragma unroll
  for (int mt = 0; mt < 4; mt++){
#pragma unroll
    for (int r = 0; r < 4; r++){
      int rl = wm * 64 + mt * 16 + quad * 4 + r;  // C/D: col=lane&15, row=quad*4+reg (m89)
      float l[4];
#pragma unroll
      for (int nt = 0; nt < 4; nt++) l[nt] = fmaf(acc[mt][nt][r], descale, bv[nt]);
      if (bn == 0 && wn == 0 && c16 == 0) blank_g[lin0 + rl] = l[0];
      if (ownL && c16 == tgc){
        float v = l[0];
#pragma unroll
        for (int k = 1; k < 4; k++) v = (ntO == k) ? l[k] : v;
        lbl_g[lin0 + rl] = v;
      }
      float s = __expf(l[0]) + __expf(l[1]) + __expf(l[2]) + __expf(l[3]);
      s += __shfl_xor(s, 1, 64);
      s += __shfl_xor(s, 2, 64);
      s += __shfl_xor(s, 4, 64);
      s += __shfl_xor(s, 8, 64);
      if (c16 == 0) redS[wn][rl] = s;
    }
  }
  __syncthreads();
  if (tid < 128)
    ps[(size_t)bn * cM + lin0 + tid] = redS[0][tid] + redS[1][tid];
}

// ------------- RNN-T alpha DP, (u,t) LDS layout (round-6 proven) -------------
// LDS index u*256+t; diagonal stride 255 = -1 mod 32 -> conflict-free.
// Scalar one-step prefetch (NO runtime-indexed arrays -> stays in VGPRs).
__global__ __launch_bounds__(256) void k_dp(
    const float* __restrict__ blank_g, const float* __restrict__ lbl_g,
    const float* __restrict__ ps,
    const int* __restrict__ in_len, const int* __restrict__ tgt_len,
    float* __restrict__ afin)
{
  __shared__ float sbb[cTU];   // 65 KB
  __shared__ float slb[cTU];   // 65 KB
  int b = blockIdx.x;
  size_t base = (size_t)b * cTU;
  for (int i = threadIdx.x; i < cTU; i += 256){
    size_t g = base + i;
    float S = 0.f;
#pragma unroll
    for (int p = 0; p < 8; p++) S += ps[(size_t)p * cM + g];
    float lse = __logf(S);
    sbb[i] = blank_g[g] - lse;
    slb[i] = ((i >> 8) < cU) ? (lbl_g[g] - lse) : NEGF;
  }
  __syncthreads();
  if (threadIdx.x >= 64) return;

  int u = threadIdx.x;                 // 0..63
  int til = in_len[b] - 1;
  int tl  = tgt_len[b];                // 32..64
  float Dprev = (u == 0) ? 0.f : NEGF; // D_d[u] = alpha[d-u][u]
  float D64prev = NEGF;
  bool cap64 = (tl == 64);
  int ub = u << 8;
  int ubm1 = (u - 1) << 8;

  auto loadB = [&](int d) -> float {
    int tb = d - 1 - u;
    bool v = (tb >= 0) & (tb <= cT - 1);
    float x = sbb[ub + (v ? tb : 0)];
    return v ? x : NEGF;
  };
  auto loadL = [&](int d) -> float {
    int t = d - u;
    bool v = (u >= 1) & (t >= 0) & (t <= cT - 1) & ((u - 1) < tl);
    float x = slb[(v ? ubm1 : 0) + (v ? t : 0)];
    return v ? x : NEGF;
  };

  float blv = loadB(1), lvv = loadL(1);
  for (int d = 1; d <= 319; d++){
    float blv_c = blv, lvv_c = lvv;
    blv = loadB(d + 1);
    lvv = loadL(d + 1);
    int t = d - u;
    bool tv = (t >= 0) & (t <= cT - 1);
    float up = __shfl_up(Dprev, 1, 64);
    float term1 = Dprev + blv_c;
    float term2 = up + lvv_c;
    float Dcur = tv ? logadd(term1, term2) : NEGF;
    if (u == tl && t == til)
      afin[b] = Dcur + sbb[ub + til];
    if (cap64){
      int t64 = d - 64;
      if (t64 >= 0 && t64 <= cT - 1){
        float s63 = __shfl(Dprev, 63, 64);
        float b64v = (t64 >= 1) ? sbb[(cU << 8) + (t64 - 1)] : NEGF;
        float tA = (t64 >= 1) ? (D64prev + b64v) : NEGF;
        float tB = s63 + slb[((cU - 1) << 8) + t64];
        float D64 = logadd(tA, tB);
        if (t64 == til && u == 0)
          afin[b] = D64 + sbb[(cU << 8) + til];
        D64prev = D64;
      }
    }
    Dprev = Dcur;
  }
}

__global__ void k_final(const float* __restrict__ afin, float* __restrict__ out){
  if (threadIdx.x == 0)
    out[0] = -0.25f * (afin[0] + afin[1] + afin[2] + afin[3]);
}

extern "C" void kernel_launch(void* const* d_in, const int* in_sizes, int n_in,
                              void* d_out, int out_size, void* d_ws, size_t ws_size,
                              hipStream_t stream)
{
  (void)in_sizes; (void)n_in; (void)out_size; (void)ws_size;
  const float* inputs = (const float*)d_in[0];   // (4,256,80)
  const float* W_enc  = (const float*)d_in[1];   // (80,512)
  const float* emb    = (const float*)d_in[2];   // (1024,512)
  const float* W_jenc = (const float*)d_in[3];   // (512,512)
  const float* W_jdec = (const float*)d_in[4];   // (512,512)
  const float* b_j    = (const float*)d_in[5];   // (512)
  const float* W_out  = (const float*)d_in[6];   // (512,1024)
  const float* b_out  = (const float*)d_in[7];   // (1024)
  const int* targets  = (const int*)d_in[8];     // (4,64)
  const int* in_len   = (const int*)d_in[9];     // (4)
  const int* tgt_len  = (const int*)d_in[10];    // (4)

  char* w = (char*)d_ws;
  auto alloc = [&](size_t bytes){ char* p = w; w += (bytes + 255) & ~(size_t)255; return p; };
  float* Wcomb   = (float*)alloc((size_t)80 * 512 * 4);
  float* e       = (float*)alloc((size_t)1024 * 512 * 4);
  float* dmatb   = (float*)alloc((size_t)260 * 512 * 4);
  float* blank_g = (float*)alloc((size_t)cM * 4);
  float* lbl_g   = (float*)alloc((size_t)cM * 4);
  float* ps      = (float*)alloc((size_t)8 * cM * 4);
  float* afin    = (float*)alloc(256);
  uchar_t* Hbf8  = (uchar_t*)alloc((size_t)520 * 65536);
  uchar_t* WTf8  = (uchar_t*)alloc((size_t)4 * 131072);

  k_pre<<<202, 256, 0, stream>>>(W_enc, W_jenc, Wcomb, emb, targets, W_jdec, b_j, dmatb,
                                 W_out, WTf8);
  k_gemm_e<<<dim3(2, 256), 256, 0, stream>>>(inputs, Wcomb, e);
  k_hf<<<520, 256, 0, stream>>>(e, dmatb, Hbf8);
  k_joint<<<4160, 256, 0, stream>>>(Hbf8, WTf8, b_out, targets, ps, blank_g, lbl_g);
  k_dp<<<4, 256, 0, stream>>>(blank_g, lbl_g, ps, in_len, tgt_len, afin);
  k_final<<<1, 64, 0, stream>>>(afin, (float*)d_out);
}